// Round 11
// baseline (205.846 us; speedup 1.0000x reference)
//
#include <hip/hip_runtime.h>

typedef __attribute__((ext_vector_type(8))) short short8;
typedef __attribute__((ext_vector_type(4))) float f32x4;

static __device__ __forceinline__ unsigned short f2b(float f) {
  union { float f; unsigned int u; } v; v.f = f;
  unsigned int u = v.u;
  unsigned int r = (u + 0x7FFFu + ((u >> 16) & 1u)) >> 16;
  return (unsigned short)r;
}
static __device__ __forceinline__ float b2f(unsigned short u) {
  union { unsigned int u; float f; } v; v.u = ((unsigned int)u) << 16;
  return v.f;
}

// ---------------------------------------------------------------------------
// K0: prep. blocks 0..3576: cast feature table (core|aux|zero) + weight to
// bf16. block 3577: build Wtq (f32 transposed proj weights) + bias pack.
// Proj weights stay f32: dots feed floor(); discontinuous bilinear weights.
// ---------------------------------------------------------------------------
__global__ __launch_bounds__(256) void setup_kernel(
    const float* __restrict__ core, const float* __restrict__ aux,
    const float* __restrict__ wgt,
    const float* __restrict__ off_w, const float* __restrict__ off_b,
    const float* __restrict__ pw_w,  const float* __restrict__ pw_b,
    const float* __restrict__ mw_w,  const float* __restrict__ mw_b,
    unsigned short* __restrict__ tab, unsigned short* __restrict__ wB,
    float* __restrict__ Wtq, float* __restrict__ bb)
{
  if (blockIdx.x < 3577) {
    const long TAB = 12001L * 256;
    const long WN  = 256L * 2304;
    long i = ((long)blockIdx.x * 256 + threadIdx.x) * 4;
    float4 v;
    unsigned short* dst;
    if (i < TAB) {
      long row = i >> 8;
      if (row < 8000)        v = *(const float4*)(core + i);
      else if (row < 12000)  v = *(const float4*)(aux + (i - 8000L * 256));
      else                   v = make_float4(0.f, 0.f, 0.f, 0.f);
      dst = tab + i;
    } else {
      long j = i - TAB;
      if (j >= WN) return;
      v = *(const float4*)(wgt + j);
      dst = wB + j;
    }
    *(ushort4*)dst = make_ushort4(f2b(v.x), f2b(v.y), f2b(v.z), f2b(v.w));
    return;
  }
  // ---- transpose proj weights: Wtq[i][d] = {W_all[d][4i..4i+3]}
  for (int e = threadIdx.x; e < 16384; e += 256) {
    int i = e >> 8;
    int d = (e >> 2) & 63;
    int j = e & 3;
    int c = i * 4 + j;
    float v;
    if (d < 36)      v = off_w[d * 256 + c];
    else if (d < 54) v = pw_w[(d - 36) * 256 + c];
    else if (d < 63) v = mw_w[(d - 54) * 256 + c];
    else             v = 0.f;
    Wtq[(i * 64 + d) * 4 + j] = v;
  }
  if (threadIdx.x < 64) {
    int d = threadIdx.x;
    float b;
    if (d < 36)      b = off_b[d];
    else if (d < 54) b = pw_b[d - 36];
    else if (d < 63) b = mw_b[d - 54];
    else             b = 0.f;
    bb[d] = b;
  }
}

// ---------------------------------------------------------------------------
// K1: proj. 500 blocks x 256 thr (4 waves x 4 rows). Lane d computes dot d;
// Wtq read coalesced b128, x read wave-uniform. Then 288 (row,k,p) tasks.
// Reference's NON-standard bilinear: w[g] = delta[x_ids[g]]*(1-delta)[y_ids[g]],
// x_ids=[1,0,1,0], y_ids=[1,1,0,0] -> f1 = gx?dx:dy ; f2 = gy?(1-dx):(1-dy)
// ---------------------------------------------------------------------------
__global__ __launch_bounds__(256) void proj_kernel(
    const float* __restrict__ core,
    const float* __restrict__ Wtq, const float* __restrict__ bb,
    const int* __restrict__ id_map, const int* __restrict__ roi_ids,
    const int* __restrict__ pos_ids,
    int* __restrict__ gids, float* __restrict__ wts)
{
  __shared__ float dots[16][64];
  const int tid  = threadIdx.x;
  const int lane = tid & 63;
  const int wv   = tid >> 6;
  const int nbase = blockIdx.x * 16 + wv * 4;

  float acc0 = 0.f, acc1 = 0.f, acc2 = 0.f, acc3 = 0.f;
  const float4* W4 = (const float4*)Wtq;
  #pragma unroll 4
  for (int i = 0; i < 64; ++i) {
    const float4 w = W4[i * 64 + lane];
    const float4 x0 = *(const float4*)(core + (long)(nbase + 0) * 256 + i * 4);
    const float4 x1 = *(const float4*)(core + (long)(nbase + 1) * 256 + i * 4);
    const float4 x2 = *(const float4*)(core + (long)(nbase + 2) * 256 + i * 4);
    const float4 x3 = *(const float4*)(core + (long)(nbase + 3) * 256 + i * 4);
    acc0 += w.x * x0.x + w.y * x0.y + w.z * x0.z + w.w * x0.w;
    acc1 += w.x * x1.x + w.y * x1.y + w.z * x1.z + w.w * x1.w;
    acc2 += w.x * x2.x + w.y * x2.y + w.z * x2.z + w.w * x2.w;
    acc3 += w.x * x3.x + w.y * x3.y + w.z * x3.z + w.w * x3.w;
  }
  const float b = bb[lane];
  dots[wv * 4 + 0][lane] = acc0 + b;
  dots[wv * 4 + 1][lane] = acc1 + b;
  dots[wv * 4 + 2][lane] = acc2 + b;
  dots[wv * 4 + 3][lane] = acc3 + b;
  __syncthreads();

  #pragma unroll
  for (int round = 0; round < 2; ++round) {
    int task = round * 256 + tid;
    if (task < 288) {
      int nl = task / 18;
      int kp = task - nl * 18;
      int k = kp >> 1, p = kp & 1;
      int n = blockIdx.x * 16 + nl;
      float x = dots[nl][k*4 + p*2 + 0] + (float)pos_ids[n*2 + 0];
      float y = dots[nl][k*4 + p*2 + 1] + (float)pos_ids[n*2 + 1];
      float fx = floorf(x), fy = floorf(y);
      float dx = x - fx, dy = y - fy;
      int bx = (int)fx, by = (int)fy;
      float l0 = dots[nl][36 + k*2], l1 = dots[nl][36 + k*2 + 1];
      float mmax = fmaxf(l0, l1);
      float e0 = __expf(l0 - mmax), e1 = __expf(l1 - mmax);
      float pwv = (p ? e1 : e0) / (e0 + e1);
      float mwv = 1.f / (1.f + __expf(-dots[nl][54 + k]));
      float wb  = pwv * mwv;
      const int* imap = id_map + roi_ids[n] * 4096;
      int base = ((n * 9 + k) * 2 + p) * 4;
      #pragma unroll
      for (int g = 0; g < 4; ++g) {
        int gx = g & 1, gy = g >> 1;
        int cx = bx + gx, cy = by + gy;
        bool pad = ((cx | cy) < 0) | (cx >= 64) | (cy >= 64);
        int cxc = min(max(cx, 0), 63), cyc = min(max(cy, 0), 63);
        int gid = pad ? 12000 : imap[cyc * 64 + cxc];
        float f1 = gx ? dx : dy;
        float f2 = gy ? (1.f - dx) : (1.f - dy);
        gids[base + g] = gid;
        wts[base + g]  = wb * f1 * f2;
      }
    }
  }
}

// ---------------------------------------------------------------------------
// K2: fused gather+GEMM v2. 250 blocks x 512 thr (8 waves). BM=32, BN=256.
// Per TAP (9 phases): stage A (32 rows x 256 cols, gathered+weighted, bf16)
// and B (W[:,tap*256:+256], 256x256 bf16) into padded LDS; then 32 MFMA/wave.
// sampled is never materialized. 2 barriers/tap. W & tab are L2-resident.
// ---------------------------------------------------------------------------
__global__ __launch_bounds__(512, 2) void gg2_kernel(
    const unsigned short* __restrict__ tab,
    const unsigned short* __restrict__ W,
    const int* __restrict__ gids, const float* __restrict__ wts,
    const float* __restrict__ bias, float* __restrict__ out)
{
  __shared__ __align__(16) unsigned short As[32][264];
  __shared__ __align__(16) unsigned short Bs[256][264];

  const int t    = threadIdx.x;
  const int m0   = blockIdx.x * 32;
  const int lane = t & 63;
  const int wv   = t >> 6;        // 0..7
  const int wr   = wv >> 2;       // 0..1 (M)
  const int wc   = wv & 3;        // 0..3 (N)
  const int brow = t >> 1;        // 0..255 (B-stage row)
  const int bh   = t & 1;         // half-row

  f32x4 acc[4] = {};

  for (int tap = 0; tap < 9; ++tap) {
    __syncthreads();   // previous MFMA phase done reading LDS
    // ---- stage A: wave wv gathers rows wv*4 .. wv*4+3 (512B coalesced each)
    #pragma unroll
    for (int r = 0; r < 4; ++r) {
      const int row = wv * 4 + r;
      const long gb = (long)(m0 + row) * 72 + tap * 8;
      float a0 = 0.f, a1 = 0.f, a2 = 0.f, a3 = 0.f;
      #pragma unroll
      for (int j = 0; j < 8; ++j) {
        const int   g = gids[gb + j];          // wave-uniform
        const float w = wts[gb + j];           // wave-uniform
        const ushort4 tv = *(const ushort4*)(tab + (long)g * 256 + lane * 4);
        a0 += w * b2f(tv.x); a1 += w * b2f(tv.y);
        a2 += w * b2f(tv.z); a3 += w * b2f(tv.w);
      }
      *(ushort4*)&As[row][lane * 4] =
          make_ushort4(f2b(a0), f2b(a1), f2b(a2), f2b(a3));
    }
    // ---- stage B: thread covers 128 cols (256 B) of its W row slice
    {
      const unsigned short* src = W + (long)brow * 2304 + tap * 256 + bh * 128;
      #pragma unroll
      for (int u = 0; u < 16; ++u) {
        const uint4 v = *(const uint4*)(src + u * 8);      // 16B = 8 bf16
        *(uint4*)&Bs[brow][bh * 128 + u * 8] = v;
      }
    }
    __syncthreads();
    // ---- MFMA: wave tile 16x64, K=256 for this tap
    #pragma unroll
    for (int kc = 0; kc < 8; ++kc) {
      const int kk = kc * 32 + (lane >> 4) * 8;
      const short8 af = *(const short8*)&As[wr * 16 + (lane & 15)][kk];
      #pragma unroll
      for (int nf = 0; nf < 4; ++nf) {
        const short8 bf = *(const short8*)&Bs[wc * 64 + nf * 16 + (lane & 15)][kk];
        acc[nf] = __builtin_amdgcn_mfma_f32_16x16x32_bf16(af, bf, acc[nf], 0, 0, 0);
      }
    }
  }

  // ---- epilogue
  const int orow = m0 + wr * 16 + (lane >> 4) * 4;
  #pragma unroll
  for (int nf = 0; nf < 4; ++nf) {
    const int col = wc * 64 + nf * 16 + (lane & 15);
    const float bs = bias[col];
    #pragma unroll
    for (int r = 0; r < 4; ++r)
      out[(long)(orow + r) * 256 + col] = acc[nf][r] + bs;
  }
}

// ---------------------------------------------------------------------------
extern "C" void kernel_launch(void* const* d_in, const int* in_sizes, int n_in,
                              void* d_out, int out_size, void* d_ws, size_t ws_size,
                              hipStream_t stream)
{
  const float* core   = (const float*)d_in[0];
  const float* aux    = (const float*)d_in[1];
  const float* off_w  = (const float*)d_in[2];
  const float* off_b  = (const float*)d_in[3];
  const float* pw_w   = (const float*)d_in[4];
  const float* pw_b   = (const float*)d_in[5];
  const float* mw_w   = (const float*)d_in[6];
  const float* mw_b   = (const float*)d_in[7];
  const float* wgt    = (const float*)d_in[8];
  const float* bias   = (const float*)d_in[9];
  const int* id_map   = (const int*)d_in[10];
  const int* roi_ids  = (const int*)d_in[11];
  const int* pos_ids  = (const int*)d_in[12];
  char* ws = (char*)d_ws;

  unsigned short* tab = (unsigned short*)(ws);              // 12001*256*2
  unsigned short* wB  = (unsigned short*)(ws + 6144512);    // 256*2304*2
  int*            gd  = (int*)           (ws + 7324160);    // 8000*72*4
  float*          wt  = (float*)         (ws + 9628160);    // 8000*72*4
  float*          Wtq = (float*)         (ws + 11932160);   // 64*64*4 f32
  float*          bb  = (float*)         (ws + 11997696);   // 64 f32
  float* out = (float*)d_out;

  hipLaunchKernelGGL(setup_kernel, dim3(3578), dim3(256), 0, stream,
                     core, aux, wgt, off_w, off_b, pw_w, pw_b, mw_w, mw_b,
                     tab, wB, Wtq, bb);
  hipLaunchKernelGGL(proj_kernel, dim3(500), dim3(256), 0, stream,
                     core, Wtq, bb, id_map, roi_ids, pos_ids, gd, wt);
  hipLaunchKernelGGL(gg2_kernel, dim3(250), dim3(512), 0, stream,
                     tab, wB, gd, wt, bias, out);
}